// Round 3
// baseline (37.368 us; speedup 1.0000x reference)
//
#include <hip/hip_runtime.h>
#include <hip/hip_bf16.h>

#define NV 8192
#define NF 16384
#define BATCH 32
#define RAWCAP 64   // raw bucket capacity; raw deg ~ Poisson(12), P(>64) ~ 1e-31

typedef unsigned short ushort_t;

// ---------------------------------------------------------------------------
// Kernel 1: scatter the 6 directed edges of each face into per-vertex buckets.
// bucket[v][k] = k-th raw (possibly duplicated) neighbor entry of v.
// ---------------------------------------------------------------------------
__global__ __launch_bounds__(256)
void scatter_faces(const int* __restrict__ faces,
                   int* __restrict__ cnt_raw,
                   ushort_t* __restrict__ bucket, int nf) {
    int f = blockIdx.x * blockDim.x + threadIdx.x;
    if (f >= nf) return;
    int a = faces[f * 3 + 0];
    int b = faces[f * 3 + 1];
    int c = faces[f * 3 + 2];
    #define PUT(r, cc) { int p = atomicAdd(&cnt_raw[r], 1); \
                         if (p < RAWCAP) bucket[(r) * RAWCAP + p] = (ushort_t)(cc); }
    PUT(a, b); PUT(b, a);
    PUT(b, c); PUT(c, b);
    PUT(c, a); PUT(a, c);
    #undef PUT
}

// ---------------------------------------------------------------------------
// Kernel 2: one wave per vertex — dedup the raw bucket (exact .set(-1)
// semantics), compute deg (distinct values INCLUDING self — the row-norm
// divisor), and emit the neighbor list (self excluded) SORTED ascending so
// downstream float sums are bitwise deterministic.
//   info[v] = deg | (cnt << 8)
//   nbr[k*NV + v] = k-th smallest distinct neighbor of v
// ---------------------------------------------------------------------------
__global__ __launch_bounds__(256)
void dedup_kernel(const int* __restrict__ cnt_raw,
                  const ushort_t* __restrict__ bucket,
                  unsigned* __restrict__ info,
                  ushort_t* __restrict__ nbr) {
    const int v    = blockIdx.x * 4 + (threadIdx.x >> 6);
    const int lane = threadIdx.x & 63;

    int craw = cnt_raw[v];
    if (craw > RAWCAP) craw = RAWCAP;

    // lane k holds raw entry k (sentinel for idle lanes)
    int val = (lane < craw) ? (int)bucket[v * RAWCAP + lane] : 0x10000;

    // mark duplicates: dup if any earlier lane holds the same value
    bool dup = false;
    for (int j = 0; j + 1 < craw; ++j) {
        int vj = __shfl(val, j);
        if (lane > j && val == vj) dup = true;
    }

    const bool validv = (lane < craw) && !dup;       // distinct values incl self
    const unsigned long long vm = __ballot(validv);
    const int deg = __popcll(vm);

    const bool keep = validv && (val != v);          // list excludes self
    const unsigned long long km = __ballot(keep);
    const int cnt = __popcll(km);

    // stable position = number of kept values smaller than mine (values distinct)
    int rank = 0;
    for (int j = 0; j < craw; ++j) {
        int vj = __shfl(val, j);
        int kj = __shfl(keep ? 1 : 0, j);
        if (kj && vj < val) ++rank;
    }

    if (keep) nbr[rank * NV + v] = (ushort_t)val;
    if (lane == 0) info[v] = (unsigned)deg | ((unsigned)cnt << 8);
}

// ---------------------------------------------------------------------------
// Kernel 3: gather + fused final reduction.
// Grid = 32 batches x 8 vertex-groups, 1024 thr/block. Stage x[b] (96 KB) in
// LDS; thread t owns vertex v = g*1024+t: sum neighbors from LDS,
// y = x[v] - sum/deg, r = |y|^2; block-reduce -> partials; last block writes
// out[b] = sum_g partials[b*8+g] / NV (deterministic order).
// ---------------------------------------------------------------------------
__global__ __launch_bounds__(1024)
void gather_kernel(const float* __restrict__ x,
                   const unsigned* __restrict__ info,
                   const ushort_t* __restrict__ nbr,
                   float* __restrict__ partials,
                   int* __restrict__ counter,
                   float* __restrict__ out) {
    __shared__ float lx[NV * 3];     // 96 KiB
    __shared__ float red[16];
    __shared__ int isLast;

    const int t = threadIdx.x;
    const int b = blockIdx.x >> 3;
    const int g = blockIdx.x & 7;

    // stage x[b]: 24576 floats = 6144 float4, coalesced
    const float4* xs = reinterpret_cast<const float4*>(x + (size_t)b * NV * 3);
    float4* ls = reinterpret_cast<float4*>(lx);
    #pragma unroll
    for (int i = 0; i < 6; ++i) ls[t + i * 1024] = xs[t + i * 1024];
    __syncthreads();

    const int v = g * 1024 + t;
    const unsigned iv = info[v];
    const int dv = (int)(iv & 0xFFu);
    const int cv = (int)(iv >> 8);

    float s0 = 0.f, s1 = 0.f, s2 = 0.f;
    for (int k = 0; k < cv; ++k) {
        const int w = (int)nbr[k * NV + v] * 3;
        s0 += lx[w];
        s1 += lx[w + 1];
        s2 += lx[w + 2];
    }

    float r = 0.f;
    if (dv > 0) {
        const float inv = 1.0f / (float)dv;
        const float y0 = lx[v * 3]     - s0 * inv;
        const float y1 = lx[v * 3 + 1] - s1 * inv;
        const float y2 = lx[v * 3 + 2] - s2 * inv;
        r = y0 * y0 + y1 * y1 + y2 * y2;
    }

    // deterministic block reduction over 1024 threads
    #pragma unroll
    for (int off = 32; off > 0; off >>= 1) r += __shfl_down(r, off);
    if ((t & 63) == 0) red[t >> 6] = r;
    __syncthreads();

    if (t == 0) {
        float s = 0.f;
        #pragma unroll
        for (int i = 0; i < 16; ++i) s += red[i];
        __hip_atomic_store(&partials[blockIdx.x], s,
                           __ATOMIC_RELAXED, __HIP_MEMORY_SCOPE_AGENT);
        int old = __hip_atomic_fetch_add(counter, 1,
                                         __ATOMIC_ACQ_REL, __HIP_MEMORY_SCOPE_AGENT);
        isLast = (old == (int)gridDim.x - 1);
    }
    __syncthreads();

    if (isLast && t < BATCH) {
        float s = 0.f;
        #pragma unroll
        for (int gg = 0; gg < 8; ++gg)
            s += __hip_atomic_load(&partials[t * 8 + gg],
                                   __ATOMIC_RELAXED, __HIP_MEMORY_SCOPE_AGENT);
        out[t] = s / (float)NV;
    }
}

extern "C" void kernel_launch(void* const* d_in, const int* in_sizes, int n_in,
                              void* d_out, int out_size, void* d_ws, size_t ws_size,
                              hipStream_t stream) {
    const float* x   = (const float*)d_in[0];   // (32, 8192, 3) f32
    const int* faces = (const int*)d_in[1];     // (16384, 3) i32
    float* out       = (float*)d_out;           // (32,) f32

    char* ws = (char*)d_ws;
    int*      cnt_raw = (int*)ws;                              // 32 KiB
    int*      counter = (int*)(ws + (size_t)NV * 4);           // 4 B (zeroed with cnt_raw)
    ushort_t* bucket  = (ushort_t*)(ws + (size_t)NV * 4 + 256);         // 1 MiB
    ushort_t* nbr     = (ushort_t*)((char*)bucket + (size_t)NV * RAWCAP * 2); // 1 MiB
    unsigned* info    = (unsigned*)((char*)nbr + (size_t)NV * RAWCAP * 2);    // 32 KiB
    float*    partials= (float*)(info + NV);                   // 1 KiB

    // zero raw counters + completion counter (ws is poisoned, never re-poisoned)
    hipMemsetAsync(cnt_raw, 0, (size_t)NV * 4 + 256, stream);

    scatter_faces<<<(NF + 255) / 256, 256, 0, stream>>>(faces, cnt_raw, bucket, NF);
    dedup_kernel<<<NV / 4, 256, 0, stream>>>(cnt_raw, bucket, info, nbr);
    gather_kernel<<<BATCH * 8, 1024, 0, stream>>>(x, info, nbr, partials, counter, out);
}